// Round 10
// baseline (90.061 us; speedup 1.0000x reference)
//
#include <hip/hip_runtime.h>
#include <cfloat>
#include <cstdint>

#define GBM 64
#define GBN 64
#define GBK 64
#define GPAD 68     // 68*4=272B rows: 16B-aligned for b128 frags

#define G_    169
#define D_    1024
#define H_    512
#define NSW   6     // stream waves (waves 0..5); waves 6,7 produce z
#define NCHUNK 128  // 8-row z/feat chunks
#define ROWG  8
#define GRPF  1352  // ROWG*G_ floats per chunk
#define NV    338   // GRPF/4 float4 per chunk
#define NBUF  3     // triple buffer -> 2-chunk lookahead
#define SPL   8     // split-K slices

typedef unsigned int u32;

__device__ __forceinline__ void gload_lds16(const float* g, float* l) {
    __builtin_amdgcn_global_load_lds(
        (const __attribute__((address_space(1))) u32*)g,
        (__attribute__((address_space(3))) u32*)l, 16, 0, 0);
}

// stage one 8x169 chunk: 6 gload_lds16 per wave (j=5 partially masked; still 6 vmcnt)
__device__ __forceinline__ void stage_group(const float* gsrc, float* ldsbase, int lane) {
    #pragma unroll
    for (int j = 0; j < 6; j++) {
        int idx = j * 64 + lane;
        if (idx < NV)
            gload_lds16(gsrc + 4 * idx, ldsbase + j * 256);
    }
}

// ---- split-K GEMM: py[s][M][N] partial of A[M,K] @ B[K,N], one 64^3 tile/block
__global__ __launch_bounds__(256) void gemm_splitk(
    const float* __restrict__ A, const float* __restrict__ B,
    float* __restrict__ Cpart, int M, int N, int K)
{
    __shared__ __align__(16) float Asm[GBK][GPAD];
    __shared__ __align__(16) float Bsm[GBK][GPAD];
    int t  = threadIdx.x;
    int m0 = blockIdx.y * GBM, n0 = blockIdx.x * GBN;
    int ks = blockIdx.z * GBK;

    #pragma unroll
    for (int i = 0; i < 4; i++) {
        int v = t + 256 * i;
        int m = v >> 4, k4 = (v & 15) * 4;
        float4 x = *(const float4*)&A[(size_t)(m0 + m) * K + ks + k4];
        Asm[k4 + 0][m] = x.x; Asm[k4 + 1][m] = x.y;
        Asm[k4 + 2][m] = x.z; Asm[k4 + 3][m] = x.w;
    }
    #pragma unroll
    for (int i = 0; i < 4; i++) {
        int v = t + 256 * i;
        int r = v >> 4, c4 = (v & 15) * 4;
        *(float4*)&Bsm[r][c4] = *(const float4*)&B[(size_t)(ks + r) * N + n0 + c4];
    }
    __syncthreads();

    int r4 = (t >> 4) * 4, c4 = (t & 15) * 4;
    float acc[4][4] = {{0.f}};
    #pragma unroll
    for (int kk = 0; kk < GBK; kk++) {
        float4 a = *(const float4*)&Asm[kk][r4];
        float4 b = *(const float4*)&Bsm[kk][c4];
        float av[4] = {a.x, a.y, a.z, a.w};
        float bv[4] = {b.x, b.y, b.z, b.w};
        #pragma unroll
        for (int i = 0; i < 4; i++)
            #pragma unroll
            for (int j = 0; j < 4; j++) acc[i][j] += av[i] * bv[j];
    }
    float* Cp = Cpart + (size_t)blockIdx.z * M * N;
    #pragma unroll
    for (int i = 0; i < 4; i++) {
        float4 v = {acc[i][0], acc[i][1], acc[i][2], acc[i][3]};
        *(float4*)&Cp[(size_t)(m0 + r4 + i) * N + n0 + c4] = v;
    }
}

// ---- feat_final: per block b -- z produced in-block by waves 6,7 while ------
// waves 0..5 stream feat via counted-vmcnt DMA pipeline; then finalize.
__global__ __launch_bounds__(512) void feat_final(
    const float* __restrict__ feat, const float* __restrict__ py,
    const float* __restrict__ W_vs,
    const float* __restrict__ boxes, const float* __restrict__ masks,
    const float* __restrict__ b_ts, const float* __restrict__ b_vs,
    const int* __restrict__ kptr,
    float* __restrict__ out_box, float* __restrict__ out_mask,
    float* __restrict__ out_max,
    int bs, int AN, int CH, int CM)
{
    __shared__ __align__(16) float buf[NSW][NBUF][GRPF];   // 97 KB
    __shared__ __align__(16) float zs[D_];
    __shared__ __align__(16) float ycopy[2][H_];
    __shared__ float accw[NSW * 176];
    __shared__ int   zp[2];
    __shared__ float ms[176];
    __shared__ int   selg[176];
    __shared__ float simv[176];
    __shared__ float simall[176];
    __shared__ float redw[8];
    __shared__ float bbs;
    __shared__ int   selp[2];

    const int b = blockIdx.x;
    const int t = threadIdx.x;
    const int w = t >> 6, lane = t & 63;

    if (t == 0) { zp[0] = 0; zp[1] = 0; }
    __syncthreads();

    if (w >= NSW) {
        // ================= z-producer wave (pw = 0 or 1) =================
        const int pw = w - NSW;
        // build y = sum_s py[s][b] + b_ts into private LDS copy
        {
            int l4 = lane * 4;
            float4 s0 = *(const float4*)&b_ts[l4];
            float4 s1 = *(const float4*)&b_ts[256 + l4];
            #pragma unroll
            for (int s = 0; s < SPL; s++) {
                const float* pyb = &py[((size_t)s * bs + b) * H_];
                float4 a0 = *(const float4*)&pyb[l4];
                float4 a1 = *(const float4*)&pyb[256 + l4];
                s0.x += a0.x; s0.y += a0.y; s0.z += a0.z; s0.w += a0.w;
                s1.x += a1.x; s1.y += a1.y; s1.z += a1.z; s1.w += a1.w;
            }
            *(float4*)&ycopy[pw][l4] = s0;
            *(float4*)&ycopy[pw][256 + l4] = s1;
        }
        asm volatile("s_waitcnt lgkmcnt(0)" ::: "memory");
        // lane's y segment (64 floats) into regs
        float4 yv[16];
        {
            const float* yb = &ycopy[pw][(lane & 7) * 64];
            #pragma unroll
            for (int j = 0; j < 16; j++) yv[j] = *(const float4*)&yb[4 * j];
        }
        const int myrow = lane >> 3;
        for (int i = 0; i < NCHUNK / 2; i++) {
            int c = 2 * i + pw;                       // global chunk id
            const float* wr = &W_vs[(size_t)(8 * c + myrow) * H_ + (lane & 7) * 64];
            float part = 0.f;
            #pragma unroll
            for (int j = 0; j < 16; j++) {
                float4 v = *(const float4*)&wr[4 * j];
                part += v.x * yv[j].x + v.y * yv[j].y + v.z * yv[j].z + v.w * yv[j].w;
            }
            part += __shfl_xor(part, 1);
            part += __shfl_xor(part, 2);
            part += __shfl_xor(part, 4);
            if ((lane & 7) == 0) zs[8 * c + myrow] = part;
            asm volatile("s_waitcnt lgkmcnt(0)" ::: "memory");  // zs visible
            if (lane == 0) ((volatile int*)zp)[pw] = i + 1;     // publish
        }
    } else {
        // ================= stream wave: chunks g = w, w+6, w+12, ... ======
        const int n = (NCHUNK - 1 - w) / NSW + 1;     // 21 or 22
        const float* gsrc = feat + (size_t)b * D_ * G_;
        stage_group(gsrc + (size_t)w * GRPF,           buf[w][0], lane);
        stage_group(gsrc + (size_t)(w + NSW) * GRPF,   buf[w][1], lane);

        float acc0 = 0.f, acc1 = 0.f, acc2 = 0.f;
        const bool g2 = lane < (G_ - 128);            // 41 lanes
        for (int i = 0; i < n; i++) {
            const int g = w + NSW * i;
            if (i + 2 < n)
                stage_group(gsrc + (size_t)(w + NSW * (i + 2)) * GRPF,
                            buf[w][(i + 2) % NBUF], lane);
            // wait for z chunk g (spin overlaps DMA flight)
            {
                int par = g & 1, need = (g >> 1) + 1;
                while (((volatile int*)zp)[par] < need)
                    __builtin_amdgcn_s_sleep(2);
            }
            asm volatile("s_waitcnt lgkmcnt(0)" ::: "memory");
            if (i + 2 < n)      asm volatile("s_waitcnt vmcnt(12)" ::: "memory");
            else if (i + 1 < n) asm volatile("s_waitcnt vmcnt(6)"  ::: "memory");
            else                asm volatile("s_waitcnt vmcnt(0)"  ::: "memory");
            __builtin_amdgcn_sched_barrier(0);
            const float* bp = buf[w][i % NBUF];
            const float* zpv = &zs[8 * g];
            #pragma unroll
            for (int r = 0; r < ROWG; r++) {
                float zv = zpv[r];
                acc0 += bp[r * G_ + lane] * zv;
                acc1 += bp[r * G_ + lane + 64] * zv;
                if (g2) acc2 += bp[r * G_ + lane + 128] * zv;
            }
        }
        accw[w * 176 + lane]      = acc0;
        accw[w * 176 + lane + 64] = acc1;
        if (g2) accw[w * 176 + lane + 128] = acc2;
    }
    __syncthreads();

    // ======================= finalize for batch b =========================
    int k = *kptr; if (k > G_) k = G_;

    if (t < G_) {
        float s = 0.f;
        #pragma unroll
        for (int ww = 0; ww < NSW; ww++) s += accw[ww * 176 + t];
        simall[t] = s;
        const float* bp = boxes + (size_t)(b * G_ + t) * AN * CH;
        float o = 0.f;
        for (int a = 0; a < AN; a++) o += bp[a * CH + 4];
        ms[t] = o / (float)AN;
    }
    // bb = b_vs . y  (y in ycopy[0])
    {
        float part = b_vs[t] * ycopy[0][t];   // H_ == 512 == blockDim
        #pragma unroll
        for (int off = 32; off > 0; off >>= 1) part += __shfl_down(part, off);
        if (lane == 0) redw[w] = part;
    }
    __syncthreads();
    if (t == 0) {
        float s = 0.f;
        #pragma unroll
        for (int ww = 0; ww < 8; ww++) s += redw[ww];
        bbs = s;
    }

    // exact top-k via rank (value desc, index asc) -- matches lax.top_k ties
    if (t < G_) {
        float mv = ms[t];
        int rank = 0;
        for (int g = 0; g < G_; g++) {
            float o = ms[g];
            rank += (int)((o > mv) | ((o == mv) & (g < t)));
        }
        if (rank < k) selg[rank] = t;
    }
    __syncthreads();

    if (t < k) simv[t] = simall[selg[t]];
    __syncthreads();

    if (t == 0) {
        float best = -FLT_MAX; int br = 0;
        for (int r = 0; r < k; r++) if (simv[r] > best) { best = simv[r]; br = r; }
        int gs = selg[br];
        const float* bp = boxes + (size_t)(b * G_ + gs) * AN * CH;
        float bo = -FLT_MAX; int ai = 0;
        for (int a = 0; a < AN; a++) { float o = bp[a * CH + 4]; if (o > bo) { bo = o; ai = a; } }
        float cx = bp[ai * CH + 0], cy = bp[ai * CH + 1];
        float ww = bp[ai * CH + 2], hh = bp[ai * CH + 3];
        float x1 = cx - ww * 0.5f, y1 = cy - hh * 0.5f;
        out_box[(size_t)b * CH + 0] = x1;
        out_box[(size_t)b * CH + 1] = y1;
        out_box[(size_t)b * CH + 2] = x1 + ww;
        out_box[(size_t)b * CH + 3] = y1 + hh;
        for (int c = 4; c < CH; c++) out_box[(size_t)b * CH + c] = bp[ai * CH + c];
        out_max[b] = best + bbs;
        selp[0] = gs; selp[1] = ai;
    }
    __syncthreads();
    if (t < CM) {
        out_mask[(size_t)b * CM + t] =
            masks[((size_t)(b * G_ + selp[0]) * AN + selp[1]) * CM + t];
    }
}

extern "C" void kernel_launch(void* const* d_in, const int* in_sizes, int n_in,
                              void* d_out, int out_size, void* d_ws, size_t ws_size,
                              hipStream_t stream)
{
    const float* boxes = (const float*)d_in[0];
    const float* masks = (const float*)d_in[1];
    const float* feat  = (const float*)d_in[2];
    const float* lang  = (const float*)d_in[3];
    const float* W_vs  = (const float*)d_in[4];
    const float* b_vs  = (const float*)d_in[5];
    const float* W_ts  = (const float*)d_in[6];
    const float* b_ts  = (const float*)d_in[7];
    const int*   kptr  = (const int*)d_in[8];

    int H  = in_sizes[5];                  // 512
    int bs = in_sizes[3] / H;              // 256
    int AN = 3;
    int CH = in_sizes[0] / (bs * G_ * AN); // 5
    int CM = in_sizes[1] / (bs * G_ * AN); // 32

    float* py = (float*)d_ws;              // SPL*bs*H

    float* out_box  = (float*)d_out;
    float* out_mask = out_box + (size_t)bs * CH;
    float* out_max  = out_mask + (size_t)bs * CM;

    // py = split-K partials of lang @ W_ts
    dim3 g1(H / GBN, bs / GBM, SPL);
    gemm_splitk<<<g1, 256, 0, stream>>>(lang, W_ts, py, bs, H, H);
    // z (in-block, wave-specialized) + feat stream + finalize
    feat_final<<<bs, 512, 0, stream>>>(feat, py, W_vs, boxes, masks, b_ts, b_vs,
                                       kptr, out_box, out_mask, out_max,
                                       bs, AN, CH, CM);
}

// Round 11
// 60.879 us; speedup vs baseline: 1.4793x; 1.4793x over previous
//
#include <hip/hip_runtime.h>
#include <cfloat>
#include <cstdint>

#define GBM 64
#define GBN 64
#define GBK 64
#define GPAD 68     // 68*4=272B rows: 16B-aligned for b128 frags

#define G_    169
#define D_    1024
#define DSPLIT 8    // d-chunks per batch (blocks.x)
#define ROWG  4     // rows per staged chunk
#define NGRP  8     // chunks per wave (32 rows/wave)
#define CHF   676   // ROWG*G_ floats per chunk
#define CNV   169   // CHF/4 float4 per chunk
#define NBUF  3     // triple buffer -> 2-chunk lookahead
#define SPL   8     // split-K slices

typedef unsigned int u32;

__device__ __forceinline__ void gload_lds16(const float* g, float* l) {
    __builtin_amdgcn_global_load_lds(
        (const __attribute__((address_space(1))) u32*)g,
        (__attribute__((address_space(3))) u32*)l, 16, 0, 0);
}

// stage one 4x169 chunk: 3 gload_lds16 per wave (j=2 masked to 41 lanes)
__device__ __forceinline__ void stage4(const float* g, float* l, int lane) {
    #pragma unroll
    for (int j = 0; j < 3; j++) {
        int idx = j * 64 + lane;
        if (idx < CNV)
            gload_lds16(g + 4 * idx, l + j * 256);
    }
}

// ---- split-K GEMM: py[s][M][N] partial of A[M,K] @ B[K,N], one 64^3 tile/block
__global__ __launch_bounds__(256) void gemm_splitk(
    const float* __restrict__ A, const float* __restrict__ B,
    float* __restrict__ Cpart, int M, int N, int K)
{
    __shared__ __align__(16) float Asm[GBK][GPAD];
    __shared__ __align__(16) float Bsm[GBK][GPAD];
    int t  = threadIdx.x;
    int m0 = blockIdx.y * GBM, n0 = blockIdx.x * GBN;
    int ks = blockIdx.z * GBK;

    #pragma unroll
    for (int i = 0; i < 4; i++) {
        int v = t + 256 * i;
        int m = v >> 4, k4 = (v & 15) * 4;
        float4 x = *(const float4*)&A[(size_t)(m0 + m) * K + ks + k4];
        Asm[k4 + 0][m] = x.x; Asm[k4 + 1][m] = x.y;
        Asm[k4 + 2][m] = x.z; Asm[k4 + 3][m] = x.w;
    }
    #pragma unroll
    for (int i = 0; i < 4; i++) {
        int v = t + 256 * i;
        int r = v >> 4, c4 = (v & 15) * 4;
        *(float4*)&Bsm[r][c4] = *(const float4*)&B[(size_t)(ks + r) * N + n0 + c4];
    }
    __syncthreads();

    int r4 = (t >> 4) * 4, c4 = (t & 15) * 4;
    float acc[4][4] = {{0.f}};
    #pragma unroll
    for (int kk = 0; kk < GBK; kk++) {
        float4 a = *(const float4*)&Asm[kk][r4];
        float4 b = *(const float4*)&Bsm[kk][c4];
        float av[4] = {a.x, a.y, a.z, a.w};
        float bv[4] = {b.x, b.y, b.z, b.w};
        #pragma unroll
        for (int i = 0; i < 4; i++)
            #pragma unroll
            for (int j = 0; j < 4; j++) acc[i][j] += av[i] * bv[j];
    }
    float* Cp = Cpart + (size_t)blockIdx.z * M * N;
    #pragma unroll
    for (int i = 0; i < 4; i++) {
        float4 v = {acc[i][0], acc[i][1], acc[i][2], acc[i][3]};
        *(float4*)&Cp[(size_t)(m0 + r4 + i) * N + n0 + c4] = v;
    }
}

// ---- gemm2: pz[s][M][N] partial of (sum_s py + b_ts)[M,K] @ W[N,K]^T -------
__global__ __launch_bounds__(256) void gemm2_fused(
    const float* __restrict__ py, const float* __restrict__ b_ts,
    const float* __restrict__ W, float* __restrict__ pz,
    int M, int N, int K)
{
    __shared__ __align__(16) float Asm[GBK][GPAD];
    __shared__ __align__(16) float Bsm[GBK][GPAD];
    int t  = threadIdx.x;
    int m0 = blockIdx.y * GBM, n0 = blockIdx.x * GBN;
    int ks = blockIdx.z * GBK;

    #pragma unroll
    for (int i = 0; i < 4; i++) {                    // A = reduced y tile
        int v = t + 256 * i;
        int m = v >> 4, h4 = (v & 15) * 4;
        float4 x = *(const float4*)&b_ts[ks + h4];
        #pragma unroll
        for (int s = 0; s < SPL; s++) {              // 8 independent loads
            float4 p = *(const float4*)&py[((size_t)s * M + m0 + m) * K + ks + h4];
            x.x += p.x; x.y += p.y; x.z += p.z; x.w += p.w;
        }
        Asm[h4 + 0][m] = x.x; Asm[h4 + 1][m] = x.y;
        Asm[h4 + 2][m] = x.z; Asm[h4 + 3][m] = x.w;
    }
    #pragma unroll
    for (int i = 0; i < 4; i++) {                    // B^T tile
        int v = t + 256 * i;
        int n = v >> 4, k4 = (v & 15) * 4;
        float4 x = *(const float4*)&W[(size_t)(n0 + n) * K + ks + k4];
        Bsm[k4 + 0][n] = x.x; Bsm[k4 + 1][n] = x.y;
        Bsm[k4 + 2][n] = x.z; Bsm[k4 + 3][n] = x.w;
    }
    __syncthreads();

    int r4 = (t >> 4) * 4, c4 = (t & 15) * 4;
    float acc[4][4] = {{0.f}};
    #pragma unroll
    for (int kk = 0; kk < GBK; kk++) {
        float4 a = *(const float4*)&Asm[kk][r4];
        float4 b = *(const float4*)&Bsm[kk][c4];
        float av[4] = {a.x, a.y, a.z, a.w};
        float bv[4] = {b.x, b.y, b.z, b.w};
        #pragma unroll
        for (int i = 0; i < 4; i++)
            #pragma unroll
            for (int j = 0; j < 4; j++) acc[i][j] += av[i] * bv[j];
    }
    float* Cp = pz + (size_t)blockIdx.z * M * N;
    #pragma unroll
    for (int i = 0; i < 4; i++) {
        float4 v = {acc[i][0], acc[i][1], acc[i][2], acc[i][3]};
        *(float4*)&Cp[(size_t)(m0 + r4 + i) * N + n0 + c4] = v;
    }
}

// ---- feat.z partials: block (ds,b) covers a 128-d chunk; 4 waves x 32 rows -
// z in registers (shfl broadcast), per-wave triple-buffered DMA pipeline with
// counted vmcnt(6/3/0); no block barrier until the final reduction.
// LDS ~35 KB -> 4 blocks/CU = 16 waves/CU.
__global__ __launch_bounds__(256) void feat_dot(
    const float* __restrict__ feat, const float* __restrict__ pz,
    float* __restrict__ s_part, int bs)
{
    __shared__ __align__(16) float buf[4][NBUF][CHF];   // 32.4 KB
    __shared__ float accw[4 * 176];
    const int b = blockIdx.y, ds = blockIdx.x;
    const int t = threadIdx.x, w = t >> 6, lane = t & 63;

    // z for this wave's 32 rows -> register (lane l holds z[w*32 + (l&31)])
    float zreg = 0.f;
    {
        int zi = ds * 128 + w * 32 + (lane & 31);
        #pragma unroll
        for (int s = 0; s < SPL; s++)
            zreg += pz[((size_t)s * bs + b) * D_ + zi];
    }

    const float* gsrc = feat + ((size_t)b * D_ + ds * 128 + w * 32) * G_;
    stage4(gsrc,       buf[w][0], lane);   // 3 outstanding
    stage4(gsrc + CHF, buf[w][1], lane);   // 6 outstanding

    float acc0 = 0.f, acc1 = 0.f, acc2 = 0.f;
    const bool g2 = lane < (G_ - 128);     // 41 lanes
    for (int gi = 0; gi < NGRP; gi++) {
        if (gi + 2 < NGRP) {
            stage4(gsrc + (size_t)(gi + 2) * CHF, buf[w][(gi + 2) % NBUF], lane);
            asm volatile("s_waitcnt vmcnt(6)" ::: "memory");   // chunk gi done
        } else if (gi + 1 < NGRP) {
            asm volatile("s_waitcnt vmcnt(3)" ::: "memory");
        } else {
            asm volatile("s_waitcnt vmcnt(0)" ::: "memory");
        }
        __builtin_amdgcn_sched_barrier(0);
        const float* bp = buf[w][gi % NBUF];
        #pragma unroll
        for (int r = 0; r < ROWG; r++) {
            float zv = __shfl(zreg, gi * 4 + r, 64);
            acc0 += bp[r * G_ + lane] * zv;
            acc1 += bp[r * G_ + lane + 64] * zv;
            if (g2) acc2 += bp[r * G_ + lane + 128] * zv;
        }
    }
    accw[w * 176 + lane]      = acc0;
    accw[w * 176 + lane + 64] = acc1;
    if (g2) accw[w * 176 + lane + 128] = acc2;
    __syncthreads();
    if (t < G_) {
        float s = accw[t] + accw[176 + t] + accw[352 + t] + accw[528 + t];
        s_part[((size_t)b * G_ + t) * DSPLIT + ds] = s;
    }
}

// ---- per-batch finalize (py reduced inline; graph edge orders) -------------
__global__ __launch_bounds__(256) void finalize(
    const float* __restrict__ boxes, const float* __restrict__ masks,
    const float* __restrict__ s_part, const float* __restrict__ py,
    const float* __restrict__ b_ts, const float* __restrict__ b_vs,
    const int* __restrict__ kptr,
    float* __restrict__ out_box, float* __restrict__ out_mask,
    float* __restrict__ out_max,
    int AN, int CH, int CM, int H, int bs)
{
    __shared__ float ms[176];
    __shared__ int   selg[176];
    __shared__ float simv[176];
    __shared__ float redw[4];
    __shared__ float bb_s;
    __shared__ int   sel_pair[2];

    int b = blockIdx.x, t = threadIdx.x;
    int k = *kptr; if (k > G_) k = G_;

    if (t < G_) {
        const float* bp = boxes + (size_t)(b * G_ + t) * AN * CH;
        float s = 0.f;
        for (int a = 0; a < AN; a++) s += bp[a * CH + 4];
        ms[t] = s / (float)AN;
    }
    // bb = b_vs . (sum_s py[s][b] + b_ts)
    float part = 0.f;
    for (int h = t; h < H; h += 256) {
        float yv = b_ts[h];
        #pragma unroll
        for (int s = 0; s < SPL; s++) yv += py[((size_t)s * bs + b) * H + h];
        part += b_vs[h] * yv;
    }
    #pragma unroll
    for (int off = 32; off > 0; off >>= 1) part += __shfl_down(part, off);
    if ((t & 63) == 0) redw[t >> 6] = part;
    __syncthreads();
    if (t == 0) bb_s = redw[0] + redw[1] + redw[2] + redw[3];

    // exact top-k via rank (value desc, index asc) -- matches lax.top_k ties
    if (t < G_) {
        float mv = ms[t];
        int rank = 0;
        for (int g = 0; g < G_; g++) {
            float o = ms[g];
            rank += (int)((o > mv) | ((o == mv) & (g < t)));
        }
        if (rank < k) selg[rank] = t;
    }
    __syncthreads();

    if (t < k) {
        const float* sp = s_part + ((size_t)b * G_ + selg[t]) * DSPLIT;
        float s = 0.f;
        #pragma unroll
        for (int i = 0; i < DSPLIT; i++) s += sp[i];
        simv[t] = s;
    }
    __syncthreads();

    if (t == 0) {
        float best = -FLT_MAX; int br = 0;
        for (int r = 0; r < k; r++) if (simv[r] > best) { best = simv[r]; br = r; }
        int gs = selg[br];
        const float* bp = boxes + (size_t)(b * G_ + gs) * AN * CH;
        float bo = -FLT_MAX; int ai = 0;
        for (int a = 0; a < AN; a++) { float o = bp[a * CH + 4]; if (o > bo) { bo = o; ai = a; } }
        float cx = bp[ai * CH + 0], cy = bp[ai * CH + 1];
        float w  = bp[ai * CH + 2], hh = bp[ai * CH + 3];
        float x1 = cx - w * 0.5f, y1 = cy - hh * 0.5f;
        out_box[(size_t)b * CH + 0] = x1;
        out_box[(size_t)b * CH + 1] = y1;
        out_box[(size_t)b * CH + 2] = x1 + w;
        out_box[(size_t)b * CH + 3] = y1 + hh;
        for (int c = 4; c < CH; c++) out_box[(size_t)b * CH + c] = bp[ai * CH + c];
        out_max[b] = best + bb_s;
        sel_pair[0] = gs; sel_pair[1] = ai;
    }
    __syncthreads();
    if (t < CM) {
        out_mask[(size_t)b * CM + t] =
            masks[((size_t)(b * G_ + sel_pair[0]) * AN + sel_pair[1]) * CM + t];
    }
}

extern "C" void kernel_launch(void* const* d_in, const int* in_sizes, int n_in,
                              void* d_out, int out_size, void* d_ws, size_t ws_size,
                              hipStream_t stream)
{
    const float* boxes = (const float*)d_in[0];
    const float* masks = (const float*)d_in[1];
    const float* feat  = (const float*)d_in[2];
    const float* lang  = (const float*)d_in[3];
    const float* W_vs  = (const float*)d_in[4];
    const float* b_vs  = (const float*)d_in[5];
    const float* W_ts  = (const float*)d_in[6];
    const float* b_ts  = (const float*)d_in[7];
    const int*   kptr  = (const int*)d_in[8];

    int H  = in_sizes[5];                  // 512
    int D  = in_sizes[4] / H;              // 1024
    int bs = in_sizes[3] / H;              // 256
    int AN = 3;
    int CH = in_sizes[0] / (bs * G_ * AN); // 5
    int CM = in_sizes[1] / (bs * G_ * AN); // 32

    float* py     = (float*)d_ws;                       // SPL*bs*H
    float* pz     = py + (size_t)SPL * bs * H;          // SPL*bs*D
    float* s_part = pz + (size_t)SPL * bs * D;          // bs*G_*DSPLIT

    float* out_box  = (float*)d_out;
    float* out_mask = out_box + (size_t)bs * CH;
    float* out_max  = out_mask + (size_t)bs * CM;

    // py = split-K partials of lang @ W_ts
    dim3 g1(H / GBN, bs / GBM, SPL);
    gemm_splitk<<<g1, 256, 0, stream>>>(lang, W_ts, py, bs, H, H);
    // pz = split-K partials of (sum py + b_ts) @ W_vs^T
    dim3 g2(D / GBN, bs / GBM, SPL);
    gemm2_fused<<<g2, 256, 0, stream>>>(py, b_ts, W_vs, pz, bs, D, H);
    // s_part = feat . z partials, 2048 blocks, 16 waves/CU
    dim3 gC(DSPLIT, bs);
    feat_dot<<<gC, 256, 0, stream>>>(feat, pz, s_part, bs);
    // finalize per batch
    finalize<<<bs, 256, 0, stream>>>(boxes, masks, s_part, py, b_ts, b_vs, kptr,
                                     out_box, out_mask, out_max,
                                     AN, CH, CM, H, bs);
}